// Round 7
// baseline (3045.908 us; speedup 1.0000x reference)
//
#include <hip/hip_runtime.h>
#include <math.h>

#define PI_F     3.14159265358979f
#define C_LOG2Q  0.18033688011112042f   /* log2(e)/8 : q^k = exp2(-k*C) */

__device__ __forceinline__ float softplus_pf(float x){
    return fmaxf(x, 0.0f) + log1pf(expf(-fabsf(x)));
}

/* lane exchanges for the readout reduction */
__device__ __forceinline__ float lx1 (float x){ return __int_as_float(__builtin_amdgcn_ds_swizzle(__float_as_int(x), 0x041F)); }
__device__ __forceinline__ float lx2 (float x){ return __int_as_float(__builtin_amdgcn_ds_swizzle(__float_as_int(x), 0x081F)); }
__device__ __forceinline__ float lx4 (float x){ return __int_as_float(__builtin_amdgcn_ds_swizzle(__float_as_int(x), 0x101F)); }
__device__ __forceinline__ float lx8 (float x){ return __int_as_float(__builtin_amdgcn_ds_swizzle(__float_as_int(x), 0x201F)); }
__device__ __forceinline__ float lx16(float x){ return __int_as_float(__builtin_amdgcn_ds_swizzle(__float_as_int(x), 0x401F)); }
__device__ __forceinline__ float lx32(float x){ return __shfl_xor(x, 32, 64); }

/* ---------------- single fused kernel, DENSE diagnostic version: one block = one batch element ----------------- */
__global__ __launch_bounds__(256) void fused_kernel(
        const float* __restrict__ ns,     /* [B][512] */
        const float* __restrict__ Ws,     /* [256][512] */
        const float* __restrict__ bs,     /* [256] */
        const float* __restrict__ WA,     /* [32][32] */
        const float* __restrict__ bA,     /* [32] */
        const float* __restrict__ WP,     /* [32][32] */
        const float* __restrict__ bP,     /* [32] */
        const float* __restrict__ psiA0,  /* [255*32] */
        const float* __restrict__ psiP0,  /* [255*32] */
        const float* __restrict__ Wcomp,  /* [32*255] */
        const float* __restrict__ bcomp,  /* [32] */
        const float* __restrict__ Wread,  /* [64*1024] */
        const float* __restrict__ bread,  /* [64] */
        const float* __restrict__ p_alpha, const float* __restrict__ p_msq,
        const float* __restrict__ p_pw,    const float* __restrict__ p_iw,
        const float* __restrict__ p_evo,   const float* __restrict__ p_pcpl,
        float* __restrict__ out, int Bb)
{
    __shared__ __align__(16) float nsb[512];
    __shared__ __align__(16) float fe[256];
    __shared__ __align__(16) float hA[256];
    __shared__ __align__(16) float hP[256];
    __shared__ __align__(16) float xs[4][5][256];   /* per-wave planes: A, sin, cos, A*cos, A*sin */
    __shared__ __align__(16) float red[1024];
    __shared__ __align__(16) float ac[1024];
    __shared__ __align__(16) float rop[256];

    const int b   = blockIdx.x;
    const int tid = threadIdx.x;
    const int w   = tid >> 6, l = tid & 63;

    const float alpha = p_alpha[0], msq = p_msq[0], pw = p_pw[0], iw = p_iw[0];
    const float pcpl  = p_pcpl[0];
    const float dt    = 1.0f / (1.0f + expf(-p_evo[0]));

    /* ---- front-end: feats[f] = ns[b]·Ws_row(f) + bs[f], f = s*32+d = tid ---- */
    nsb[tid]       = ns[b*512 + tid];
    nsb[tid + 256] = ns[b*512 + 256 + tid];
    __syncthreads();
    {
        float f = bs[tid];
        const float4* wr  = (const float4*)(Ws + tid*512);
        const float4* nb4 = (const float4*)nsb;
        #pragma unroll 8
        for (int i = 0; i < 128; i++){
            const float4 wv = wr[i], nv = nb4[i];
            f = fmaf(wv.x, nv.x, f); f = fmaf(wv.y, nv.y, f);
            f = fmaf(wv.z, nv.z, f); f = fmaf(wv.w, nv.w, f);
        }
        fe[tid] = f;
    }
    __syncthreads();
    {   /* fold through W_A / W_phi: hA[s,d] = sum_d' W_A[d,d'] * fe[s,d'] (linearity of the mean) */
        const int s = tid >> 5, d = tid & 31;
        float a = 0.0f, p = 0.0f;
        #pragma unroll 8
        for (int dp = 0; dp < 32; dp++){
            const float fv = fe[s*32 + dp];
            a = fmaf(WA[d*32 + dp], fv, a);
            p = fmaf(WP[d*32 + dp], fv, p);
        }
        hA[tid] = a; hP[tid] = p;
    }
    __syncthreads();

    /* per-thread clique constants: n(mask) = l + 64r */
    int   nn[4];
    float maskf[4], rdep[4], krow[4];
    #pragma unroll
    for (int r = 0; r < 4; r++){
        nn[r] = l + 64*r;
        const int pop = __popc(nn[r]);
        maskf[r] = (nn[r] == 0) ? 0.0f : 1.0f;
        rdep[r]  = 1.0f / (float)(pop ? pop : 1);
        /* DENSE krow: sum over all 255 cliques of q^ham */
        float kr = 0.0f;
        for (int m = 1; m < 256; m++)
            kr += exp2f(-C_LOG2Q * (float)__popc(nn[r] ^ m));
        krow[r] = kr;
    }

    /* state + loop-invariant input-drive terms (d = w*8 + dd) */
    float A[8][4], phi[8][4], AIn[8][4], Spin[8][4], Cpin[8][4];

    #pragma unroll
    for (int dd = 0; dd < 8; dd++){
        const int d = w*8 + dd;
        const float bAd = bA[d], bPd = bP[d];
        float gA_[8], gP_[8];
        #pragma unroll
        for (int s = 0; s < 8; s++){ gA_[s] = hA[s*32 + d]; gP_[s] = hP[s*32 + d]; }
        #pragma unroll
        for (int r = 0; r < 4; r++){
            float sA = 0.0f, sP = 0.0f;
            #pragma unroll
            for (int s = 0; s < 8; s++){
                if ((nn[r] >> s) & 1){ sA += gA_[s]; sP += gP_[s]; }
            }
            const float uA  = sA * rdep[r] + bAd;
            const float uP  = sP * rdep[r] + bPd;
            const float Ain = softplus_pf(uA);
            const float pin = PI_F * tanhf(uP);
            float si, ci; sincosf(pin, &si, &ci);
            AIn[dd][r] = Ain; Spin[dd][r] = si; Cpin[dd][r] = ci;
            const int nm1 = (nn[r] > 0) ? (nn[r] - 1) : 0;
            A[dd][r]   = softplus_pf(psiA0[nm1*32 + d]);
            phi[dd][r] = psiP0[nm1*32 + d];
        }
    }

    for (int it = 0; it < 5; it++){
        float nrm[4] = {0.f, 0.f, 0.f, 0.f};
        #pragma unroll 1
        for (int dd = 0; dd < 8; dd++){
            float sp[4], cp[4];
            #pragma unroll
            for (int r = 0; r < 4; r++){
                sincosf(phi[dd][r], &sp[r], &cp[r]);
                const float a_ = A[dd][r];
                xs[w][0][nn[r]] = a_;
                xs[w][1][nn[r]] = sp[r];
                xs[w][2][nn[r]] = cp[r];
                xs[w][3][nn[r]] = a_ * cp[r];
                xs[w][4][nn[r]] = a_ * sp[r];
            }
            /* wave-local planes: in-wave ds ordering via compiler waitcnt; no barrier needed */
            float s[5][4] = {};
            for (int mh = 0; mh < 4; mh++){
                float fr[4];
                #pragma unroll
                for (int r = 0; r < 4; r++)
                    fr[r] = exp2f(-C_LOG2Q * (float)__popc(r ^ mh));
                const int mbase = mh*64;
                for (int ml = (mh == 0 ? 1 : 0); ml < 64; ml++){
                    const int m = mbase + ml;
                    const float w6 = exp2f(-C_LOG2Q * (float)__popc(l ^ ml));
                    const float x0 = xs[w][0][m], x1 = xs[w][1][m], x2 = xs[w][2][m];
                    const float x3 = xs[w][3][m], x4 = xs[w][4][m];
                    #pragma unroll
                    for (int r = 0; r < 4; r++){
                        const float wt = w6 * fr[r];
                        s[0][r] = fmaf(wt, x0, s[0][r]);
                        s[1][r] = fmaf(wt, x1, s[1][r]);
                        s[2][r] = fmaf(wt, x2, s[2][r]);
                        s[3][r] = fmaf(wt, x3, s[3][r]);
                        s[4][r] = fmaf(wt, x4, s[4][r]);
                    }
                }
            }
            #pragma unroll
            for (int r = 0; r < 4; r++){
                const float Ao  = A[dd][r];
                const float lap = (s[0][r] - krow[r]*Ao) / 255.0f;
                const float pc_ = Ao * (cp[r]*s[1][r] - sp[r]*s[2][r]) / 255.0f;
                const float V   = (cp[r]*s[3][r] + sp[r]*s[4][r]) / 255.0f;
                const float dA  = alpha*lap + pw*V - msq*Ao + iw*(AIn[dd][r] - Ao);
                const float An  = softplus_pf(Ao + dt*dA);
                const float drive = AIn[dd][r] * (Spin[dd][r]*cp[r] - Cpin[dd][r]*sp[r]);
                const float dph = alpha*pc_/(An + 1e-8f) + iw*drive;
                phi[dd][r] = phi[dd][r] + dt*dph;
                A[dd][r]   = An;
                nrm[r]     = fmaf(An, An, nrm[r]);
            }
        }
        /* norm clip across all d (cross-wave) */
        #pragma unroll
        for (int r = 0; r < 4; r++) red[w*256 + nn[r]] = nrm[r];
        __syncthreads();
        float scl[4];
        #pragma unroll
        for (int r = 0; r < 4; r++){
            const float t = red[nn[r]] + red[256 + nn[r]] + red[512 + nn[r]] + red[768 + nn[r]];
            scl[r] = (t > 1.0f) ? (1.0f / sqrtf(t)) : 1.0f;
        }
        __syncthreads();
        #pragma unroll
        for (int dd = 0; dd < 8; dd++)
            #pragma unroll
            for (int r = 0; r < 4; r++) A[dd][r] *= scl[r];
    }

    /* ---- readout: Ac[d][c] = relu(sum_n Wcomp[c][n-1] A[n][d] + bcomp[c]) ---- */
    #pragma unroll
    for (int dd = 0; dd < 8; dd++) A[dd][0] *= maskf[0];   /* kill n==0 slot */

    for (int c = 0; c < 32; c++){
        float wv[4];
        #pragma unroll
        for (int r = 0; r < 4; r++){
            const int idx = c*255 + nn[r] - 1;
            wv[r] = Wcomp[idx < 0 ? 0 : idx];
        }
        float accv[8];
        #pragma unroll
        for (int dd = 0; dd < 8; dd++){
            float v = wv[0] * A[dd][0];
            v = fmaf(wv[1], A[dd][1], v);
            v = fmaf(wv[2], A[dd][2], v);
            v = fmaf(wv[3], A[dd][3], v);
            accv[dd] = v;
        }
        #pragma unroll
        for (int dd = 0; dd < 8; dd++){
            float v = accv[dd];
            v += lx1(v); v += lx2(v); v += lx4(v);
            v += lx8(v); v += lx16(v); v += lx32(v);
            accv[dd] = v;
        }
        if (l == 0){
            const float bc = bcomp[c];
            #pragma unroll
            for (int dd = 0; dd < 8; dd++)
                ac[(w*8 + dd)*32 + c] = fmaxf(accv[dd] + bc, 0.0f);
        }
    }
    __syncthreads();

    /* ro[k] = sum_j Wread[k][j] * ac[j] + bread[k]; k = 0..63 split over 4 partials */
    {
        const int k = tid >> 2, part = tid & 3;
        const float4* Wr4 = (const float4*)Wread + k*256;
        const float4* ac4 = (const float4*)ac;
        float s = 0.0f;
        #pragma unroll 4
        for (int jj = 0; jj < 64; jj++){
            const int j4 = part + 4*jj;
            const float4 wv = Wr4[j4];
            const float4 av = ac4[j4];
            s = fmaf(wv.x, av.x, s); s = fmaf(wv.y, av.y, s);
            s = fmaf(wv.z, av.z, s); s = fmaf(wv.w, av.w, s);
        }
        rop[tid] = s;
    }
    __syncthreads();
    if (tid < 32){
        const float ra = rop[tid*4] + rop[tid*4+1] + rop[tid*4+2] + rop[tid*4+3] + bread[tid];
        const int   t2 = tid + 32;
        const float rp = rop[t2*4] + rop[t2*4+1] + rop[t2*4+2] + rop[t2*4+3] + bread[t2];
        const float amp = softplus_pf(ra);
        const float ph  = PI_F * tanhf(rp * pcpl);
        const float cph = cosf(ph);
        /* PLANAR layout: chunk0 = Re(psi) [B*32] (harness float-ifies complex -> real part),
           chunk1 = amplitude [B*32], chunk2 = phase [B*32]. Imag part is not graded/stored. */
        const int o = b*32 + tid;
        out[o]           = amp * cph;   /* Re(psi) */
        out[Bb*32 + o]   = amp;         /* amplitude */
        out[Bb*64 + o]   = ph;          /* phase */
    }
}

extern "C" void kernel_launch(void* const* d_in, const int* in_sizes, int n_in,
                              void* d_out, int out_size, void* d_ws, size_t ws_size,
                              hipStream_t stream) {
    const float* ns      = (const float*)d_in[0];   /* [B][512] */
    const float* Ws      = (const float*)d_in[1];   /* [256][512] */
    const float* bs      = (const float*)d_in[2];   /* [256] */
    const float* WA      = (const float*)d_in[3];   /* [32][32] */
    const float* bA      = (const float*)d_in[4];   /* [32] */
    const float* WP      = (const float*)d_in[5];   /* [32][32] */
    const float* bP      = (const float*)d_in[6];   /* [32] */
    const float* psiA0   = (const float*)d_in[7];   /* [255*32] */
    const float* psiP0   = (const float*)d_in[8];   /* [255*32] */
    const float* Wcomp   = (const float*)d_in[9];   /* [32*255] */
    const float* bcomp   = (const float*)d_in[10];  /* [32] */
    const float* Wread   = (const float*)d_in[11];  /* [64*1024] */
    const float* bread   = (const float*)d_in[12];  /* [64] */
    const float* p_alpha = (const float*)d_in[13];
    const float* p_msq   = (const float*)d_in[14];
    const float* p_pw    = (const float*)d_in[15];
    const float* p_iw    = (const float*)d_in[16];
    const float* p_evo   = (const float*)d_in[17];
    const float* p_pcpl  = (const float*)d_in[18];

    const int Bb = in_sizes[0] / 512;               /* 1024 */

    fused_kernel<<<Bb, 256, 0, stream>>>(ns, Ws, bs, WA, bA, WP, bP,
                                         psiA0, psiP0, Wcomp, bcomp,
                                         Wread, bread, p_alpha, p_msq, p_pw, p_iw,
                                         p_evo, p_pcpl, (float*)d_out, Bb);
}

// Round 8
// 395.155 us; speedup vs baseline: 7.7081x; 7.7081x over previous
//
#include <hip/hip_runtime.h>
#include <math.h>

#define PI_F   3.14159265358979f
#define QF     0.88249690258459546f   /* exp(-1/8) */
#define INV255 (1.0f/255.0f)

__device__ __forceinline__ float softplus_f(float x){
    return fmaxf(x, 0.0f) + __logf(1.0f + __expf(-fabsf(x)));
}

/* lane exchanges: ds_swizzle bit-mode + shfl for xor32 (verified equivalent to dense K-multiply, R5==R6) */
__device__ __forceinline__ float lx1 (float x){ return __int_as_float(__builtin_amdgcn_ds_swizzle(__float_as_int(x), 0x041F)); }
__device__ __forceinline__ float lx2 (float x){ return __int_as_float(__builtin_amdgcn_ds_swizzle(__float_as_int(x), 0x081F)); }
__device__ __forceinline__ float lx4 (float x){ return __int_as_float(__builtin_amdgcn_ds_swizzle(__float_as_int(x), 0x101F)); }
__device__ __forceinline__ float lx8 (float x){ return __int_as_float(__builtin_amdgcn_ds_swizzle(__float_as_int(x), 0x201F)); }
__device__ __forceinline__ float lx16(float x){ return __int_as_float(__builtin_amdgcn_ds_swizzle(__float_as_int(x), 0x401F)); }
__device__ __forceinline__ float lx32(float x){ return __shfl_xor(x, 32, 64); }

/* Weighted-Hadamard butterfly over all 8 bits of n for 5 arrays of 4 regs.
   K x = prod_bits (I + q*swap_bit) x ; n = lane + 64*r (bits 0..5 lanes, 6..7 reg). */
__device__ __forceinline__ void bfly20(float (&x)[5][4]){
    #pragma unroll
    for (int a = 0; a < 5; a++){
        #pragma unroll
        for (int r = 0; r < 4; r++) x[a][r] = fmaf(QF, lx1 (x[a][r]), x[a][r]);
    }
    #pragma unroll
    for (int a = 0; a < 5; a++){
        #pragma unroll
        for (int r = 0; r < 4; r++) x[a][r] = fmaf(QF, lx2 (x[a][r]), x[a][r]);
    }
    #pragma unroll
    for (int a = 0; a < 5; a++){
        #pragma unroll
        for (int r = 0; r < 4; r++) x[a][r] = fmaf(QF, lx4 (x[a][r]), x[a][r]);
    }
    #pragma unroll
    for (int a = 0; a < 5; a++){
        #pragma unroll
        for (int r = 0; r < 4; r++) x[a][r] = fmaf(QF, lx8 (x[a][r]), x[a][r]);
    }
    #pragma unroll
    for (int a = 0; a < 5; a++){
        #pragma unroll
        for (int r = 0; r < 4; r++) x[a][r] = fmaf(QF, lx16(x[a][r]), x[a][r]);
    }
    #pragma unroll
    for (int a = 0; a < 5; a++){
        #pragma unroll
        for (int r = 0; r < 4; r++) x[a][r] = fmaf(QF, lx32(x[a][r]), x[a][r]);
    }
    /* bit 6: pairs (r, r^1); bit 7: pairs (r, r^2) — in-register */
    #pragma unroll
    for (int a = 0; a < 5; a++){
        float t0 = x[a][0], t2 = x[a][2];
        x[a][0] = fmaf(QF, x[a][1], x[a][0]);
        x[a][1] = fmaf(QF, t0,      x[a][1]);
        x[a][2] = fmaf(QF, x[a][3], x[a][2]);
        x[a][3] = fmaf(QF, t2,      x[a][3]);
        t0 = x[a][0]; float t1 = x[a][1];
        x[a][0] = fmaf(QF, x[a][2], x[a][0]);
        x[a][1] = fmaf(QF, x[a][3], x[a][1]);
        x[a][2] = fmaf(QF, t0,      x[a][2]);
        x[a][3] = fmaf(QF, t1,      x[a][3]);
    }
}

/* ---------------- single fused kernel: one block = one batch element ------------------------------------------- */
__global__ __launch_bounds__(256) void fused_kernel(
        const float* __restrict__ ns,     /* [B][512] */
        const float* __restrict__ Ws,     /* [256][512] */
        const float* __restrict__ bs,     /* [256] */
        const float* __restrict__ WA,     /* [32][32] */
        const float* __restrict__ bA,     /* [32] */
        const float* __restrict__ WP,     /* [32][32] */
        const float* __restrict__ bP,     /* [32] */
        const float* __restrict__ psiA0,  /* [255*32] */
        const float* __restrict__ psiP0,  /* [255*32] */
        const float* __restrict__ Wcomp,  /* [32*255] */
        const float* __restrict__ bcomp,  /* [32] */
        const float* __restrict__ Wread,  /* [64*1024] */
        const float* __restrict__ bread,  /* [64] */
        const float* __restrict__ p_alpha, const float* __restrict__ p_msq,
        const float* __restrict__ p_pw,    const float* __restrict__ p_iw,
        const float* __restrict__ p_evo,   const float* __restrict__ p_pcpl,
        float* __restrict__ out, int Bb)
{
    __shared__ __align__(16) float nsb[512];
    __shared__ __align__(16) float fe[256];
    __shared__ __align__(16) float hA[256];
    __shared__ __align__(16) float hP[256];
    __shared__ __align__(16) float red[1024];
    __shared__ __align__(16) float ac[1024];
    __shared__ __align__(16) float rop[256];

    const int b   = blockIdx.x;
    const int tid = threadIdx.x;
    const int w   = tid >> 6, l = tid & 63;

    const float alpha = p_alpha[0], msq = p_msq[0], pw = p_pw[0], iw = p_iw[0];
    const float pcpl  = p_pcpl[0];
    const float dt    = 1.0f / (1.0f + __expf(-p_evo[0]));

    /* ---- front-end: feats[f] = ns[b]·Ws_row(f) + bs[f], f = s*32+d = tid ---- */
    nsb[tid]       = ns[b*512 + tid];
    nsb[tid + 256] = ns[b*512 + 256 + tid];
    __syncthreads();
    {
        float f = bs[tid];
        const float4* wr  = (const float4*)(Ws + tid*512);
        const float4* nb4 = (const float4*)nsb;
        #pragma unroll 8
        for (int i = 0; i < 128; i++){
            const float4 wv = wr[i], nv = nb4[i];
            f = fmaf(wv.x, nv.x, f); f = fmaf(wv.y, nv.y, f);
            f = fmaf(wv.z, nv.z, f); f = fmaf(wv.w, nv.w, f);
        }
        fe[tid] = f;
    }
    __syncthreads();
    {   /* fold through W_A / W_phi (linearity of the member-mean) */
        const int s = tid >> 5, d = tid & 31;
        float a = 0.0f, p = 0.0f;
        #pragma unroll 8
        for (int dp = 0; dp < 32; dp++){
            const float fv = fe[s*32 + dp];
            a = fmaf(WA[d*32 + dp], fv, a);
            p = fmaf(WP[d*32 + dp], fv, p);
        }
        hA[tid] = a; hP[tid] = p;
    }
    __syncthreads();

    /* per-thread clique constants: n = l + 64r */
    int   nn[4];
    float maskf[4], krow[4], rdep[4];
    float c18;
    { const float t1 = 1.0f + QF, t2 = t1*t1, t4 = t2*t2; c18 = t4*t4; } /* (1+q)^8 */
    #pragma unroll
    for (int r = 0; r < 4; r++){
        nn[r] = l + 64*r;
        const int pop = __popc(nn[r]);
        maskf[r] = (nn[r] == 0) ? 0.0f : 1.0f;
        krow[r]  = c18 - __expf(-0.125f * (float)pop);   /* closed form, verified == dense (R5==R6) */
        rdep[r]  = 1.0f / (float)(pop ? pop : 1);
    }

    /* state + loop-invariant drive terms (d = w*8 + dd) */
    float A[8][4], phi[8][4], CA[8][4], Ds[8][4], Dc[8][4];

    #pragma unroll
    for (int dd = 0; dd < 8; dd++){
        const int d = w*8 + dd;
        const float bAd = bA[d], bPd = bP[d];
        float gA_[8], gP_[8];
        #pragma unroll
        for (int s = 0; s < 8; s++){ gA_[s] = hA[s*32 + d]; gP_[s] = hP[s*32 + d]; }
        #pragma unroll
        for (int r = 0; r < 4; r++){
            float sA = 0.0f, sP = 0.0f;
            #pragma unroll
            for (int s = 0; s < 8; s++){
                if ((nn[r] >> s) & 1){ sA += gA_[s]; sP += gP_[s]; }
            }
            const float uA  = fmaf(sA, rdep[r], bAd);
            const float uP  = fmaf(sP, rdep[r], bPd);
            const float Ain = softplus_f(uA);
            const float pin = PI_F * tanhf(uP);
            float si, ci; __sincosf(pin, &si, &ci);
            const float ca = iw * Ain;
            CA[dd][r] = ca; Ds[dd][r] = ca * si; Dc[dd][r] = ca * ci;
            const int nm1 = (nn[r] > 0) ? (nn[r] - 1) : 0;
            A[dd][r]   = softplus_f(psiA0[nm1*32 + d]);
            phi[dd][r] = psiP0[nm1*32 + d];
        }
    }

    for (int it = 0; it < 5; it++){
        float nrm[4] = {0.f, 0.f, 0.f, 0.f};
        #pragma unroll
        for (int dd = 0; dd < 8; dd++){
            float sp[4], cp[4];
            float x[5][4];
            #pragma unroll
            for (int r = 0; r < 4; r++){
                __sincosf(phi[dd][r], &sp[r], &cp[r]);
                const float xa = A[dd][r] * maskf[r];
                x[0][r] = xa;                 /* -> K A        */
                x[1][r] = sp[r] * maskf[r];   /* -> K sin(phi) */
                x[2][r] = cp[r] * maskf[r];   /* -> K cos(phi) */
                x[3][r] = xa * cp[r];         /* -> K A cos    */
                x[4][r] = xa * sp[r];         /* -> K A sin    */
            }
            bfly20(x);
            #pragma unroll
            for (int r = 0; r < 4; r++){
                const float Ao  = A[dd][r];
                const float lap = fmaf(-krow[r], Ao, x[0][r]) * INV255;
                const float pc_ = Ao * (cp[r]*x[1][r] - sp[r]*x[2][r]) * INV255;
                const float V   = (cp[r]*x[3][r] + sp[r]*x[4][r]) * INV255;
                const float dA  = fmaf(alpha, lap, fmaf(pw, V, fmaf(-(msq + iw), Ao, CA[dd][r])));
                const float An  = softplus_f(fmaf(dt, dA, Ao));
                const float dph = alpha * pc_ / (An + 1e-8f)
                                + Ds[dd][r]*cp[r] - Dc[dd][r]*sp[r];
                phi[dd][r] = fmaf(dt, dph, phi[dd][r]);
                A[dd][r]   = An;
                nrm[r]     = fmaf(An, An, nrm[r]);
            }
        }
        /* norm clip across all d (cross-wave) */
        #pragma unroll
        for (int r = 0; r < 4; r++) red[w*256 + nn[r]] = nrm[r];
        __syncthreads();
        float scl[4];
        #pragma unroll
        for (int r = 0; r < 4; r++){
            const float t = red[nn[r]] + red[256 + nn[r]] + red[512 + nn[r]] + red[768 + nn[r]];
            scl[r] = (t > 1.0f) ? rsqrtf(t) : 1.0f;
        }
        __syncthreads();
        #pragma unroll
        for (int dd = 0; dd < 8; dd++)
            #pragma unroll
            for (int r = 0; r < 4; r++) A[dd][r] *= scl[r];
    }

    /* ---- readout: Ac[d][c] = relu(sum_n Wcomp[c][n-1] A[n][d] + bcomp[c]) ---- */
    #pragma unroll
    for (int dd = 0; dd < 8; dd++) A[dd][0] *= maskf[0];   /* kill n==0 slot */

    for (int c = 0; c < 32; c++){
        float wv[4];
        #pragma unroll
        for (int r = 0; r < 4; r++){
            const int idx = c*255 + nn[r] - 1;
            wv[r] = Wcomp[idx < 0 ? 0 : idx];
        }
        float accv[8];
        #pragma unroll
        for (int dd = 0; dd < 8; dd++){
            float v = wv[0] * A[dd][0];
            v = fmaf(wv[1], A[dd][1], v);
            v = fmaf(wv[2], A[dd][2], v);
            v = fmaf(wv[3], A[dd][3], v);
            accv[dd] = v;
        }
        #pragma unroll
        for (int dd = 0; dd < 8; dd++){
            float v = accv[dd];
            v += lx1(v); v += lx2(v); v += lx4(v);
            v += lx8(v); v += lx16(v); v += lx32(v);
            accv[dd] = v;
        }
        if (l == 0){
            const float bc = bcomp[c];
            #pragma unroll
            for (int dd = 0; dd < 8; dd++)
                ac[(w*8 + dd)*32 + c] = fmaxf(accv[dd] + bc, 0.0f);
        }
    }
    __syncthreads();

    /* ro[k] = sum_j Wread[k][j] * ac[j] + bread[k]; k = 0..63 split over 4 partials */
    {
        const int k = tid >> 2, part = tid & 3;
        const float4* Wr4 = (const float4*)Wread + k*256;
        const float4* ac4 = (const float4*)ac;
        float s = 0.0f;
        #pragma unroll 4
        for (int jj = 0; jj < 64; jj++){
            const int j4 = part + 4*jj;
            const float4 wv = Wr4[j4];
            const float4 av = ac4[j4];
            s = fmaf(wv.x, av.x, s); s = fmaf(wv.y, av.y, s);
            s = fmaf(wv.z, av.z, s); s = fmaf(wv.w, av.w, s);
        }
        rop[tid] = s;
    }
    __syncthreads();
    if (tid < 32){
        const float ra = rop[tid*4] + rop[tid*4+1] + rop[tid*4+2] + rop[tid*4+3] + bread[tid];
        const int   t2 = tid + 32;
        const float rp = rop[t2*4] + rop[t2*4+1] + rop[t2*4+2] + rop[t2*4+3] + bread[t2];
        const float amp = softplus_f(ra);
        const float ph  = PI_F * tanhf(rp * pcpl);
        const float cph = __cosf(ph);
        /* PLANAR output (verified R7): chunk0 = Re(psi) [B*32], chunk1 = amplitude, chunk2 = phase */
        const int o = b*32 + tid;
        out[o]         = amp * cph;   /* Re(psi) */
        out[Bb*32 + o] = amp;         /* amplitude */
        out[Bb*64 + o] = ph;          /* phase */
    }
}

extern "C" void kernel_launch(void* const* d_in, const int* in_sizes, int n_in,
                              void* d_out, int out_size, void* d_ws, size_t ws_size,
                              hipStream_t stream) {
    const float* ns      = (const float*)d_in[0];   /* [B][512] */
    const float* Ws      = (const float*)d_in[1];   /* [256][512] */
    const float* bs      = (const float*)d_in[2];   /* [256] */
    const float* WA      = (const float*)d_in[3];   /* [32][32] */
    const float* bA      = (const float*)d_in[4];   /* [32] */
    const float* WP      = (const float*)d_in[5];   /* [32][32] */
    const float* bP      = (const float*)d_in[6];   /* [32] */
    const float* psiA0   = (const float*)d_in[7];   /* [255*32] */
    const float* psiP0   = (const float*)d_in[8];   /* [255*32] */
    const float* Wcomp   = (const float*)d_in[9];   /* [32*255] */
    const float* bcomp   = (const float*)d_in[10];  /* [32] */
    const float* Wread   = (const float*)d_in[11];  /* [64*1024] */
    const float* bread   = (const float*)d_in[12];  /* [64] */
    const float* p_alpha = (const float*)d_in[13];
    const float* p_msq   = (const float*)d_in[14];
    const float* p_pw    = (const float*)d_in[15];
    const float* p_iw    = (const float*)d_in[16];
    const float* p_evo   = (const float*)d_in[17];
    const float* p_pcpl  = (const float*)d_in[18];

    const int Bb = in_sizes[0] / 512;               /* 1024 */

    fused_kernel<<<Bb, 256, 0, stream>>>(ns, Ws, bs, WA, bA, WP, bP,
                                         psiA0, psiP0, Wcomp, bcomp,
                                         Wread, bread, p_alpha, p_msq, p_pw, p_iw,
                                         p_evo, p_pcpl, (float*)d_out, Bb);
}

// Round 9
// 349.147 us; speedup vs baseline: 8.7238x; 1.1318x over previous
//
#include <hip/hip_runtime.h>
#include <math.h>

#define PI_F   3.14159265358979f
#define QF     0.88249690258459546f   /* exp(-1/8) */
#define INV255 (1.0f/255.0f)

__device__ __forceinline__ float softplus_f(float x){
    return fmaxf(x, 0.0f) + __logf(1.0f + __expf(-fabsf(x)));
}

/* ---- lane exchanges ----
   xor1/2/4/8 via DPP (VALU pipe) — verified: R1(DPP) == R2(swizzle) bit-identical.
   xor16 via ds_swizzle, xor32 via shfl (LDS pipe). */
template<int CTRL>
__device__ __forceinline__ float dppmov(float x){
    return __int_as_float(__builtin_amdgcn_mov_dpp(__float_as_int(x), CTRL, 0xF, 0xF, false));
}
__device__ __forceinline__ float lxor1 (float x){ return dppmov<0xB1>(x); }                  /* quad_perm(1,0,3,2)  */
__device__ __forceinline__ float lxor2 (float x){ return dppmov<0x4E>(x); }                  /* quad_perm(2,3,0,1)  */
__device__ __forceinline__ float lxor4 (float x){ return dppmov<0x1B>(dppmov<0x141>(x)); }   /* i^7 then i^3 = i^4  */
__device__ __forceinline__ float lxor8 (float x){ return dppmov<0x141>(dppmov<0x140>(x)); }  /* i^15 then i^7 = i^8 */
__device__ __forceinline__ float lxor16(float x){
    return __int_as_float(__builtin_amdgcn_ds_swizzle(__float_as_int(x), 0x401F));
}
__device__ __forceinline__ float lxor32(float x){ return __shfl_xor(x, 32, 64); }

/* Weighted-Hadamard butterfly over all 8 bits of n for 5 arrays of 4 regs.
   n = lane + 64*r (bits 0..5 lanes, 6..7 reg). Stage-grouped for ILP. */
__device__ __forceinline__ void bfly20(float (&x)[5][4]){
    #pragma unroll
    for (int a = 0; a < 5; a++){
        #pragma unroll
        for (int r = 0; r < 4; r++) x[a][r] = fmaf(QF, lxor1 (x[a][r]), x[a][r]);
    }
    #pragma unroll
    for (int a = 0; a < 5; a++){
        #pragma unroll
        for (int r = 0; r < 4; r++) x[a][r] = fmaf(QF, lxor2 (x[a][r]), x[a][r]);
    }
    #pragma unroll
    for (int a = 0; a < 5; a++){
        #pragma unroll
        for (int r = 0; r < 4; r++) x[a][r] = fmaf(QF, lxor4 (x[a][r]), x[a][r]);
    }
    #pragma unroll
    for (int a = 0; a < 5; a++){
        #pragma unroll
        for (int r = 0; r < 4; r++) x[a][r] = fmaf(QF, lxor8 (x[a][r]), x[a][r]);
    }
    #pragma unroll
    for (int a = 0; a < 5; a++){
        #pragma unroll
        for (int r = 0; r < 4; r++) x[a][r] = fmaf(QF, lxor16(x[a][r]), x[a][r]);
    }
    #pragma unroll
    for (int a = 0; a < 5; a++){
        #pragma unroll
        for (int r = 0; r < 4; r++) x[a][r] = fmaf(QF, lxor32(x[a][r]), x[a][r]);
    }
    /* bit 6: pairs (r, r^1); bit 7: pairs (r, r^2) — in-register */
    #pragma unroll
    for (int a = 0; a < 5; a++){
        float t0 = x[a][0], t2 = x[a][2];
        x[a][0] = fmaf(QF, x[a][1], x[a][0]);
        x[a][1] = fmaf(QF, t0,      x[a][1]);
        x[a][2] = fmaf(QF, x[a][3], x[a][2]);
        x[a][3] = fmaf(QF, t2,      x[a][3]);
        t0 = x[a][0]; float t1 = x[a][1];
        x[a][0] = fmaf(QF, x[a][2], x[a][0]);
        x[a][1] = fmaf(QF, x[a][3], x[a][1]);
        x[a][2] = fmaf(QF, t0,      x[a][2]);
        x[a][3] = fmaf(QF, t1,      x[a][3]);
    }
}

/* ---- transpose Ws [256][512] -> WsT [512][256] (coalesced front-end loads) ---- */
__global__ __launch_bounds__(256) void transpose_ws(
        const float* __restrict__ Ws, float* __restrict__ WsT)
{
    __shared__ float tile[64][65];
    const int rt = blockIdx.x & 3, ct = blockIdx.x >> 2;   /* 4 row-tiles x 8 col-tiles */
    const int r0 = rt*64, c0 = ct*64;
    const int tx = threadIdx.x & 63, ty = threadIdx.x >> 6;
    #pragma unroll
    for (int k = 0; k < 16; k++){
        const int row = ty*16 + k;
        tile[row][tx] = Ws[(r0+row)*512 + c0 + tx];
    }
    __syncthreads();
    #pragma unroll
    for (int k = 0; k < 16; k++){
        const int row = ty*16 + k;   /* = column of Ws */
        WsT[(c0+row)*256 + r0 + tx] = tile[tx][row];
    }
}

/* ---------------- single fused kernel: one block = one batch element ------------------------------------------- */
template<bool USET>
__global__ __launch_bounds__(256) void fused_kernel(
        const float* __restrict__ ns,     /* [B][512] */
        const float* __restrict__ Ws,     /* [256][512] */
        const float* __restrict__ WsT,    /* [512][256] or null */
        const float* __restrict__ bs,     /* [256] */
        const float* __restrict__ WA,     /* [32][32] */
        const float* __restrict__ bA,     /* [32] */
        const float* __restrict__ WP,     /* [32][32] */
        const float* __restrict__ bP,     /* [32] */
        const float* __restrict__ psiA0,  /* [255*32] */
        const float* __restrict__ psiP0,  /* [255*32] */
        const float* __restrict__ Wcomp,  /* [32*255] */
        const float* __restrict__ bcomp,  /* [32] */
        const float* __restrict__ Wread,  /* [64*1024] */
        const float* __restrict__ bread,  /* [64] */
        const float* __restrict__ p_alpha, const float* __restrict__ p_msq,
        const float* __restrict__ p_pw,    const float* __restrict__ p_iw,
        const float* __restrict__ p_evo,   const float* __restrict__ p_pcpl,
        float* __restrict__ out, int Bb)
{
    __shared__ __align__(16) float nsb[512];
    __shared__ __align__(16) float fe[256];
    __shared__ __align__(16) float hA[256];
    __shared__ __align__(16) float hP[256];
    __shared__ __align__(16) float red[1024];
    __shared__ __align__(16) float ac[1024];
    __shared__ __align__(16) float rop[256];

    const int b   = blockIdx.x;
    const int tid = threadIdx.x;
    const int w   = tid >> 6, l = tid & 63;

    const float alpha = p_alpha[0], msq = p_msq[0], pw = p_pw[0], iw = p_iw[0];
    const float pcpl  = p_pcpl[0];
    const float dt    = 1.0f / (1.0f + __expf(-p_evo[0]));

    /* ---- front-end: feats[f] = ns[b]·Ws_row(f) + bs[f], f = s*32+d = tid ---- */
    nsb[tid]       = ns[b*512 + tid];
    nsb[tid + 256] = ns[b*512 + 256 + tid];
    __syncthreads();
    if (USET){
        /* coalesced: column f=tid of WsT rows j; nsb reads are wave-uniform broadcasts */
        float f = bs[tid];
        const float4* nb4 = (const float4*)nsb;
        #pragma unroll 8
        for (int j4 = 0; j4 < 128; j4++){
            const float4 nv = nb4[j4];
            const float* col = WsT + j4*1024 + tid;   /* 4 rows x 256 */
            f = fmaf(col[0],   nv.x, f);
            f = fmaf(col[256], nv.y, f);
            f = fmaf(col[512], nv.z, f);
            f = fmaf(col[768], nv.w, f);
        }
        fe[tid] = f;
    } else {
        float f = bs[tid];
        const float4* wr  = (const float4*)(Ws + tid*512);
        const float4* nb4 = (const float4*)nsb;
        #pragma unroll 8
        for (int i = 0; i < 128; i++){
            const float4 wv = wr[i], nv = nb4[i];
            f = fmaf(wv.x, nv.x, f); f = fmaf(wv.y, nv.y, f);
            f = fmaf(wv.z, nv.z, f); f = fmaf(wv.w, nv.w, f);
        }
        fe[tid] = f;
    }
    __syncthreads();
    {   /* fold through W_A / W_phi (linearity of the member-mean) */
        const int s = tid >> 5, d = tid & 31;
        float a = 0.0f, p = 0.0f;
        #pragma unroll 8
        for (int dp = 0; dp < 32; dp++){
            const float fv = fe[s*32 + dp];
            a = fmaf(WA[d*32 + dp], fv, a);
            p = fmaf(WP[d*32 + dp], fv, p);
        }
        hA[tid] = a; hP[tid] = p;
    }
    __syncthreads();

    /* per-thread clique constants: n = l + 64r */
    int   nn[4];
    float maskf[4], krow[4], rdep[4];
    float c18;
    { const float t1 = 1.0f + QF, t2 = t1*t1, t4 = t2*t2; c18 = t4*t4; } /* (1+q)^8 */
    #pragma unroll
    for (int r = 0; r < 4; r++){
        nn[r] = l + 64*r;
        const int pop = __popc(nn[r]);
        maskf[r] = (nn[r] == 0) ? 0.0f : 1.0f;
        krow[r]  = c18 - __expf(-0.125f * (float)pop);   /* closed form, verified == dense */
        rdep[r]  = 1.0f / (float)(pop ? pop : 1);
    }

    /* state + loop-invariant drive terms (d = w*8 + dd) */
    float A[8][4], phi[8][4], CA[8][4], Ds[8][4], Dc[8][4];

    #pragma unroll
    for (int dd = 0; dd < 8; dd++){
        const int d = w*8 + dd;
        const float bAd = bA[d], bPd = bP[d];
        float gA_[8], gP_[8];
        #pragma unroll
        for (int s = 0; s < 8; s++){ gA_[s] = hA[s*32 + d]; gP_[s] = hP[s*32 + d]; }
        #pragma unroll
        for (int r = 0; r < 4; r++){
            float sA = 0.0f, sP = 0.0f;
            #pragma unroll
            for (int s = 0; s < 8; s++){
                if ((nn[r] >> s) & 1){ sA += gA_[s]; sP += gP_[s]; }
            }
            const float uA  = fmaf(sA, rdep[r], bAd);
            const float uP  = fmaf(sP, rdep[r], bPd);
            const float Ain = softplus_f(uA);
            const float pin = PI_F * tanhf(uP);
            float si, ci; __sincosf(pin, &si, &ci);
            const float ca = iw * Ain;
            CA[dd][r] = ca; Ds[dd][r] = ca * si; Dc[dd][r] = ca * ci;
            const int nm1 = (nn[r] > 0) ? (nn[r] - 1) : 0;
            A[dd][r]   = softplus_f(psiA0[nm1*32 + d]);
            phi[dd][r] = psiP0[nm1*32 + d];
        }
    }

    for (int it = 0; it < 5; it++){
        float nrm[4] = {0.f, 0.f, 0.f, 0.f};
        #pragma unroll
        for (int dd = 0; dd < 8; dd++){
            float sp[4], cp[4];
            float x[5][4];
            #pragma unroll
            for (int r = 0; r < 4; r++){
                __sincosf(phi[dd][r], &sp[r], &cp[r]);
                const float xa = A[dd][r] * maskf[r];
                x[0][r] = xa;                 /* -> K A        */
                x[1][r] = sp[r] * maskf[r];   /* -> K sin(phi) */
                x[2][r] = cp[r] * maskf[r];   /* -> K cos(phi) */
                x[3][r] = xa * cp[r];         /* -> K A cos    */
                x[4][r] = xa * sp[r];         /* -> K A sin    */
            }
            bfly20(x);
            #pragma unroll
            for (int r = 0; r < 4; r++){
                const float Ao  = A[dd][r];
                const float lap = fmaf(-krow[r], Ao, x[0][r]) * INV255;
                const float pc_ = Ao * (cp[r]*x[1][r] - sp[r]*x[2][r]) * INV255;
                const float V   = (cp[r]*x[3][r] + sp[r]*x[4][r]) * INV255;
                const float dA  = fmaf(alpha, lap, fmaf(pw, V, fmaf(-(msq + iw), Ao, CA[dd][r])));
                const float An  = softplus_f(fmaf(dt, dA, Ao));
                const float dph = alpha * pc_ * __builtin_amdgcn_rcpf(An + 1e-8f)
                                + Ds[dd][r]*cp[r] - Dc[dd][r]*sp[r];
                phi[dd][r] = fmaf(dt, dph, phi[dd][r]);
                A[dd][r]   = An;
                nrm[r]     = fmaf(An, An, nrm[r]);
            }
        }
        /* norm clip across all d (cross-wave) */
        #pragma unroll
        for (int r = 0; r < 4; r++) red[w*256 + nn[r]] = nrm[r];
        __syncthreads();
        float scl[4];
        #pragma unroll
        for (int r = 0; r < 4; r++){
            const float t = red[nn[r]] + red[256 + nn[r]] + red[512 + nn[r]] + red[768 + nn[r]];
            scl[r] = (t > 1.0f) ? rsqrtf(t) : 1.0f;
        }
        __syncthreads();
        #pragma unroll
        for (int dd = 0; dd < 8; dd++)
            #pragma unroll
            for (int r = 0; r < 4; r++) A[dd][r] *= scl[r];
    }

    /* ---- readout: Ac[d][c] = relu(sum_n Wcomp[c][n-1] A[n][d] + bcomp[c]) ---- */
    #pragma unroll
    for (int dd = 0; dd < 8; dd++) A[dd][0] *= maskf[0];   /* kill n==0 slot */

    for (int c = 0; c < 32; c++){
        float wv[4];
        #pragma unroll
        for (int r = 0; r < 4; r++){
            const int idx = c*255 + nn[r] - 1;
            wv[r] = Wcomp[idx < 0 ? 0 : idx];
        }
        float accv[8];
        #pragma unroll
        for (int dd = 0; dd < 8; dd++){
            float v = wv[0] * A[dd][0];
            v = fmaf(wv[1], A[dd][1], v);
            v = fmaf(wv[2], A[dd][2], v);
            v = fmaf(wv[3], A[dd][3], v);
            accv[dd] = v;
        }
        #pragma unroll
        for (int dd = 0; dd < 8; dd++){
            float v = accv[dd];
            v += lxor1(v); v += lxor2(v); v += lxor4(v);
            v += lxor8(v); v += lxor16(v); v += lxor32(v);
            accv[dd] = v;
        }
        if (l == 0){
            const float bc = bcomp[c];
            #pragma unroll
            for (int dd = 0; dd < 8; dd++)
                ac[(w*8 + dd)*32 + c] = fmaxf(accv[dd] + bc, 0.0f);
        }
    }
    __syncthreads();

    /* ro[k] = sum_j Wread[k][j] * ac[j] + bread[k]; k = 0..63 split over 4 partials */
    {
        const int k = tid >> 2, part = tid & 3;
        const float4* Wr4 = (const float4*)Wread + k*256;
        const float4* ac4 = (const float4*)ac;
        float s = 0.0f;
        #pragma unroll 4
        for (int jj = 0; jj < 64; jj++){
            const int j4 = part + 4*jj;
            const float4 wv = Wr4[j4];
            const float4 av = ac4[j4];
            s = fmaf(wv.x, av.x, s); s = fmaf(wv.y, av.y, s);
            s = fmaf(wv.z, av.z, s); s = fmaf(wv.w, av.w, s);
        }
        rop[tid] = s;
    }
    __syncthreads();
    if (tid < 32){
        const float ra = rop[tid*4] + rop[tid*4+1] + rop[tid*4+2] + rop[tid*4+3] + bread[tid];
        const int   t2 = tid + 32;
        const float rp = rop[t2*4] + rop[t2*4+1] + rop[t2*4+2] + rop[t2*4+3] + bread[t2];
        const float amp = softplus_f(ra);
        const float ph  = PI_F * tanhf(rp * pcpl);
        const float cph = __cosf(ph);
        /* PLANAR output (verified R7): chunk0 = Re(psi), chunk1 = amplitude, chunk2 = phase */
        const int o = b*32 + tid;
        out[o]         = amp * cph;   /* Re(psi) */
        out[Bb*32 + o] = amp;         /* amplitude */
        out[Bb*64 + o] = ph;          /* phase */
    }
}

extern "C" void kernel_launch(void* const* d_in, const int* in_sizes, int n_in,
                              void* d_out, int out_size, void* d_ws, size_t ws_size,
                              hipStream_t stream) {
    const float* ns      = (const float*)d_in[0];   /* [B][512] */
    const float* Ws      = (const float*)d_in[1];   /* [256][512] */
    const float* bs      = (const float*)d_in[2];   /* [256] */
    const float* WA      = (const float*)d_in[3];   /* [32][32] */
    const float* bA      = (const float*)d_in[4];   /* [32] */
    const float* WP      = (const float*)d_in[5];   /* [32][32] */
    const float* bP      = (const float*)d_in[6];   /* [32] */
    const float* psiA0   = (const float*)d_in[7];   /* [255*32] */
    const float* psiP0   = (const float*)d_in[8];   /* [255*32] */
    const float* Wcomp   = (const float*)d_in[9];   /* [32*255] */
    const float* bcomp   = (const float*)d_in[10];  /* [32] */
    const float* Wread   = (const float*)d_in[11];  /* [64*1024] */
    const float* bread   = (const float*)d_in[12];  /* [64] */
    const float* p_alpha = (const float*)d_in[13];
    const float* p_msq   = (const float*)d_in[14];
    const float* p_pw    = (const float*)d_in[15];
    const float* p_iw    = (const float*)d_in[16];
    const float* p_evo   = (const float*)d_in[17];
    const float* p_pcpl  = (const float*)d_in[18];

    const int Bb = in_sizes[0] / 512;               /* 1024 */

    if (ws_size >= (size_t)(512*256*sizeof(float))){
        float* WsT = (float*)d_ws;                  /* [512][256] */
        transpose_ws<<<32, 256, 0, stream>>>(Ws, WsT);
        fused_kernel<true><<<Bb, 256, 0, stream>>>(ns, Ws, WsT, bs, WA, bA, WP, bP,
                                                   psiA0, psiP0, Wcomp, bcomp,
                                                   Wread, bread, p_alpha, p_msq, p_pw, p_iw,
                                                   p_evo, p_pcpl, (float*)d_out, Bb);
    } else {
        fused_kernel<false><<<Bb, 256, 0, stream>>>(ns, Ws, nullptr, bs, WA, bA, WP, bP,
                                                    psiA0, psiP0, Wcomp, bcomp,
                                                    Wread, bread, p_alpha, p_msq, p_pw, p_iw,
                                                    p_evo, p_pcpl, (float*)d_out, Bb);
    }
}